// Round 13
// baseline (297.544 us; speedup 1.0000x reference)
//
#include <hip/hip_runtime.h>
#include <stdint.h>

#define HW   1369      // 37*37 output pixels
#define QW   39        // padded row width
#define QP   1616      // padded plane rows per (b) in Xp
#define QT   1536      // q rows in x1 (per batch)
#define CIN  1024
#define CMID 512
#define KTOT 9216      // 9 * 1024
#define NTIL 144       // K-tiles: 16 cblocks(64) * 9 taps, cblock-major tap-inner

typedef float  f32x4  __attribute__((ext_vector_type(4)));
typedef __bf16 bf16x8 __attribute__((ext_vector_type(8)));

__device__ __forceinline__ uint16_t f2bf(float f) {
  uint32_t u = __float_as_uint(f);
  u += 0x7fffu + ((u >> 16) & 1u);
  return (uint16_t)(u >> 16);
}

// global -> LDS direct copy, 16B per lane. LDS dest = wave-uniform base + lane*16.
__device__ __forceinline__ void gll16(const void* g, void* l) {
  const __attribute__((address_space(1))) uint32_t* ga =
      (const __attribute__((address_space(1))) uint32_t*)(uintptr_t)g;
  __attribute__((address_space(3))) uint32_t* la =
      (__attribute__((address_space(3))) uint32_t*)(uint32_t)(uintptr_t)l;
  __builtin_amdgcn_global_load_lds(ga, la, 16, 0, 0);
}

// ---------- prep: fmap [b][c][h][w] f32 -> Xp [b][q][c] bf16 (padded, zeroed border) ----------
__global__ void k_pad_transpose(const float* __restrict__ fmap, uint16_t* __restrict__ Xp) {
  __shared__ float t[32][33];
  const int b = blockIdx.z;
  const int c0 = blockIdx.y * 32;
  const int p0 = blockIdx.x * 32;
  const int tx = threadIdx.x, ty = threadIdx.y;
  const float* src = fmap + ((size_t)b * CIN + c0) * HW + p0;
#pragma unroll
  for (int i = 0; i < 4; ++i) {
    int cc = ty + i * 8;
    t[cc][tx] = (p0 + tx < HW) ? src[(size_t)cc * HW + tx] : 0.f;
  }
  __syncthreads();
#pragma unroll
  for (int i = 0; i < 4; ++i) {
    int pl = ty + i * 8;
    int p = p0 + pl;
    if (p < HW) {
      int h = p / 37, w = p - h * 37;
      int q = (h + 1) * QW + (w + 1);
      Xp[((size_t)b * QP + q) * CIN + c0 + tx] = f2bf(t[tx][pl]);
    }
  }
}

// ---------- prep: W1 -> B fragments in MFMA order ----------
// Bp[frag][lane][8el], frag = (t*32 + o16)*2 + kk. Lane l holds
// B[o16*16 + (l&15)][tap*1024 + cb*64 + kk*32 + (l>>4)*8 ..+8], t = cb*9+tap.
__global__ void k_pack_bfrag(const float* __restrict__ W1, uint16_t* __restrict__ Bp) {
  const int gid = blockIdx.x * 256 + threadIdx.x;   // 589824 exact
  const int lane = gid & 63;
  const int f    = gid >> 6;
  const int kk   = f & 1;
  const int o16  = (f >> 1) & 31;
  const int t    = f >> 6;
  const int cb = t / 9, tap = t - cb * 9;
  const int o   = o16 * 16 + (lane & 15);
  const int kap = kk * 32 + (lane >> 4) * 8;
  uint16_t* dst = Bp + (size_t)gid * 8;
#pragma unroll
  for (int e = 0; e < 8; ++e) {
    const int c = cb * 64 + kap + e;
    dst[e] = f2bf(W1[((size_t)o * CIN + c) * 9 + tap]);
  }
}

// ---------- prep: W2 [120][512] f32 -> W2p [128][512] bf16 ----------
__global__ void k_pack_w2(const float* __restrict__ W2, uint16_t* __restrict__ W2p) {
  int idx = blockIdx.x * 256 + threadIdx.x;
  int j = idx >> 9, o = idx & 511;
  W2p[idx] = (j < 120) ? f2bf(W2[j * 512 + o]) : (uint16_t)0;
}

// ---------- conv1: BARRIER-FREE self-paced waves ----------
// Block 192x128, 4 waves 4M x 1N (wave 48x128). Each wave's A rows are
// DISJOINT: private double-buffered 6KB LDS panel per wave (48KB/block),
// staged by the wave's own gll16 and guarded only by its own vmcnt.
// B: r12 frag-packed, per-wave coalesced global_load_dwordx4 (L1-hot, all
// 8 waves/CU share nt). NO s_barrier in the K-loop -> waves de-phase freely,
// LDS/VMEM/MFMA pipes overlap across the 2 waves/SIMD.
// Per-wave FIFO per tile: issue [bv0(t+1) x8, A(t+1) x6] after kk0, [bv1(t+1) x8]
// after kk1. Waits: vmcnt(8) at tile top (A+bv0 ready), vmcnt(14) before kk1.
__global__ __launch_bounds__(256, 2) void k_conv1(
    const uint16_t* __restrict__ Xp, const uint16_t* __restrict__ Bp,
    const float* __restrict__ b1, uint16_t* __restrict__ x1) {
  __shared__ __align__(16) uint16_t lds[24576];   // 4 waves x 2 slots x 3072 el = 48KB

  const int tid  = threadIdx.x;
  const int wid  = tid >> 6, lane = tid & 63;
  const int lrow = lane & 15, lq = lane >> 4;

  // grid: 512 blocks = 8 XCDs x 64; co-resident pair (bid, bid+256) shares nt
  const int bid = blockIdx.x;
  const int g   = (bid & 7) * 64 + (bid >> 3);
  const int mt  = g >> 2, nt = g & 3;
  const int batch = mt >> 3, qb = (mt & 7) * 192;
  const int o0 = nt * 128;
  const uint16_t* Xb = Xp + (size_t)batch * QP * CIN;
  const int qw = qb + wid * 48;            // wave's private 48 A-rows

  // staging lane mapping (64 lanes stage 6KB: row j*8+(l>>3), chunk l&7, XOR-swizzled src col)
  const int srow8 = lane >> 3;
  const int scol  = ((lane & 7) ^ srow8) * 8;   // elements

  uint16_t* myl = lds + wid * 6144;        // private region: 2 slots x 3072 el

  // fragment-read swizzled cols; lds_byte = glob_byte ^ ((row&7)<<4)
  const int xorb    = (lrow & 7) << 4;
  const int col_el0 = ((lq * 16) ^ xorb) >> 1;
  const int col_el1 = col_el0 ^ 32;

  // B frag base: + lane*8 + nt*8 o16-groups (1024 el per o16 group)
  const uint16_t* Bl = Bp + (size_t)lane * 8 + (size_t)nt * 8192;

  f32x4 acc[3][8] = {};
  bf16x8 bv0[8], bv1[8];

#define STAGEA(u) do {                                                                \
    if ((u) < NTIL) {                                                                 \
      const int cb_  = (u) / 9;                                                       \
      const int tap_ = (u) - cb_ * 9;                                                 \
      const int off_ = (tap_ / 3) * QW + tap_ % 3;                                    \
      const int c0_  = cb_ << 6;                                                      \
      uint16_t* sl = myl + ((u) & 1) * 3072;                                          \
      _Pragma("unroll")                                                               \
      for (int j = 0; j < 6; ++j)                                                     \
        gll16(Xb + (size_t)(qw + off_ + j * 8 + srow8) * CIN + c0_ + scol,            \
              sl + j * 512);                                                          \
    }                                                                                 \
  } while (0)

#define LOADBK(u, kk, BV) do {                                                        \
    if ((u) < NTIL) {                                                                 \
      const uint16_t* bq = Bl + ((size_t)(u) * 64 + (kk)) * 512;                      \
      _Pragma("unroll")                                                               \
      for (int n = 0; n < 8; ++n)                                                     \
        asm volatile("global_load_dwordx4 %0, %1, off"                                \
                     : "=v"(BV[n]) : "v"(bq + n * 1024) : "memory");                  \
    }                                                                                 \
  } while (0)

#define TILE(t, W1S, W2S, ISS) do {                                                   \
    asm volatile(W1S ::: "memory");            /* A(t) + bv0(t) ready */              \
    __builtin_amdgcn_sched_barrier(0);                                                \
    const uint16_t* As = myl + ((t) & 1) * 3072;                                      \
    bf16x8 av0[3], av1[3];                                                            \
    _Pragma("unroll")                                                                 \
    for (int m = 0; m < 3; ++m) {                                                     \
      const uint16_t* ar = As + (m * 16 + lrow) * 64;                                 \
      av0[m] = *(const bf16x8*)(ar + col_el0);                                        \
      av1[m] = *(const bf16x8*)(ar + col_el1);                                        \
    }                                                                                 \
    __builtin_amdgcn_s_setprio(1);                                                    \
    _Pragma("unroll")                                                                 \
    for (int m = 0; m < 3; ++m)                                                       \
      _Pragma("unroll")                                                               \
      for (int n = 0; n < 8; ++n)                                                     \
        acc[m][n] = __builtin_amdgcn_mfma_f32_16x16x32_bf16(                          \
            av0[m], bv0[n], acc[m][n], 0, 0, 0);                                      \
    __builtin_amdgcn_s_setprio(0);                                                    \
    if (ISS) { LOADBK((t) + 1, 0, bv0); STAGEA((t) + 1); }                            \
    asm volatile(W2S ::: "memory");            /* bv1(t) ready */                     \
    __builtin_amdgcn_sched_barrier(0);                                                \
    __builtin_amdgcn_s_setprio(1);                                                    \
    _Pragma("unroll")                                                                 \
    for (int m = 0; m < 3; ++m)                                                       \
      _Pragma("unroll")                                                               \
      for (int n = 0; n < 8; ++n)                                                     \
        acc[m][n] = __builtin_amdgcn_mfma_f32_16x16x32_bf16(                          \
            av1[m], bv1[n], acc[m][n], 0, 0, 0);                                      \
    __builtin_amdgcn_s_setprio(0);                                                    \
    if (ISS) LOADBK((t) + 1, 1, bv1);                                                 \
  } while (0)

  // prologue FIFO: bv0(0) x8, A(0) x6, bv1(0) x8  -> tile-0 waits line up
  LOADBK(0, 0, bv0);
  STAGEA(0);
  LOADBK(0, 1, bv1);

  for (int t = 0; t < NTIL - 2; t += 2) {
    TILE(t,     "s_waitcnt vmcnt(8)",  "s_waitcnt vmcnt(14)", 1);
    TILE(t + 1, "s_waitcnt vmcnt(8)",  "s_waitcnt vmcnt(14)", 1);
  }
  TILE(NTIL - 2, "s_waitcnt vmcnt(8)", "s_waitcnt vmcnt(14)", 1);
  TILE(NTIL - 1, "s_waitcnt vmcnt(8)", "s_waitcnt vmcnt(0)",  0);

  // epilogue: bias + ReLU6 -> x1 bf16
  const int qr = lq * 4;
#pragma unroll
  for (int n = 0; n < 8; ++n) {
    const int o = o0 + n * 16 + lrow;
    const float bias = b1[o];
#pragma unroll
    for (int m = 0; m < 3; ++m) {
#pragma unroll
      for (int v = 0; v < 4; ++v) {
        const int q = qw + m * 16 + qr + v;
        float x = acc[m][n][v] + bias;
        x = fminf(fmaxf(x, 0.f), 6.f);
        x1[((size_t)batch * QT + q) * CMID + o] = f2bf(x);
      }
    }
  }
#undef TILE
#undef LOADBK
#undef STAGEA
}

// ---------- conv2: out[b][h][w][j] = sum_o x1[q][o] * W2[j][o] + b2[j] ----------
__global__ __launch_bounds__(256, 2) void k_conv2(
    const uint16_t* __restrict__ x1, const uint16_t* __restrict__ W2p,
    const float* __restrict__ b2, float* __restrict__ out) {
  __shared__ __align__(16) uint16_t lA[128 * 64];
  __shared__ __align__(16) uint16_t lB[128 * 64];
  const int tid = threadIdx.x;
  const int wid = tid >> 6, lane = tid & 63;
  const int b = blockIdx.z, q0 = blockIdx.x * 128;
  const uint16_t* Ab = x1 + (size_t)b * QT * CMID;
  const int wm = wid >> 1, wn = wid & 1;
  const int lrow = lane & 15, lk = (lane >> 4) * 8;
  f32x4 acc[4][4] = {};

  for (int kt = 0; kt < 8; ++kt) {
    const int c0 = kt << 6;
#pragma unroll
    for (int i = 0; i < 4; ++i) {
      int wb = i * 256 + wid * 64;
      int chunk = wb + lane;
      int row = chunk >> 3, ch = chunk & 7;
      gll16(Ab + (size_t)(q0 + row) * CMID + c0 + ch * 8, lA + wb * 8);
      gll16(W2p + (size_t)row * CMID + c0 + ch * 8, lB + wb * 8);
    }
    __syncthreads();
#pragma unroll
    for (int kk = 0; kk < 2; ++kk) {
      bf16x8 av[4], bv[4];
#pragma unroll
      for (int mi = 0; mi < 4; ++mi)
        av[mi] = *(const bf16x8*)(lA + (wm * 64 + mi * 16 + lrow) * 64 + kk * 32 + lk);
#pragma unroll
      for (int ni = 0; ni < 4; ++ni)
        bv[ni] = *(const bf16x8*)(lB + (wn * 64 + ni * 16 + lrow) * 64 + kk * 32 + lk);
#pragma unroll
      for (int mi = 0; mi < 4; ++mi)
#pragma unroll
        for (int ni = 0; ni < 4; ++ni)
          acc[mi][ni] = __builtin_amdgcn_mfma_f32_16x16x32_bf16(av[mi], bv[ni], acc[mi][ni], 0, 0, 0);
    }
    __syncthreads();
  }

  const int qr = (lane >> 4) * 4;
#pragma unroll
  for (int ni = 0; ni < 4; ++ni) {
    int j = wn * 64 + ni * 16 + lrow;
    if (j < 120) {
      float bias = b2[j];
#pragma unroll
      for (int mi = 0; mi < 4; ++mi) {
#pragma unroll
        for (int v = 0; v < 4; ++v) {
          int q = q0 + wm * 64 + mi * 16 + qr + v;
          int h = q / QW, w = q - h * QW;
          if (h < 37 && w < 37) {
            out[((size_t)b * HW + h * 37 + w) * 120 + j] = acc[mi][ni][v] + bias;
          }
        }
      }
    }
  }
}

extern "C" void kernel_launch(void* const* d_in, const int* in_sizes, int n_in,
                              void* d_out, int out_size, void* d_ws, size_t ws_size,
                              hipStream_t stream) {
  const float* fmap = (const float*)d_in[0];
  const float* W1   = (const float*)d_in[1];
  const float* b1   = (const float*)d_in[2];
  const float* W2   = (const float*)d_in[3];
  const float* b2   = (const float*)d_in[4];
  float* out = (float*)d_out;

  uint8_t* ws = (uint8_t*)d_ws;
  const size_t XP_BYTES = (size_t)16 * QP * CIN * 2;          // 52,953,088
  const size_t BP_BYTES = (size_t)144 * 32 * 2 * 64 * 8 * 2;  //  9,437,184
  const size_t W2P_BYTES = (size_t)128 * 512 * 2;             //    131,072
  uint16_t* Xp  = (uint16_t*)ws;
  uint16_t* Bp  = (uint16_t*)(ws + XP_BYTES);
  uint16_t* W2p = (uint16_t*)(ws + XP_BYTES + BP_BYTES);
  uint16_t* x1  = (uint16_t*)(ws + XP_BYTES + BP_BYTES + W2P_BYTES);

  hipMemsetAsync(Xp, 0, XP_BYTES, stream);
  k_pad_transpose<<<dim3(43, 32, 16), dim3(32, 8), 0, stream>>>(fmap, Xp);
  k_pack_bfrag<<<dim3(2304), dim3(256), 0, stream>>>(W1, Bp);
  k_pack_w2<<<dim3(256), dim3(256), 0, stream>>>(W2, W2p);
  k_conv1<<<dim3(512), dim3(256), 0, stream>>>(Xp, Bp, b1, x1);
  k_conv2<<<dim3(12, 1, 16), dim3(256), 0, stream>>>(x1, W2p, b2, out);
}